// Round 7
// baseline (1895.630 us; speedup 1.0000x reference)
//
#include <hip/hip_runtime.h>
#include <cstdint>

// Problem dims: N=2048, IN_DIM=128, HID=64, ENC=64, B=64, SEQ=12

typedef _Float16 half8 __attribute__((ext_vector_type(8)));
typedef _Float16 half4 __attribute__((ext_vector_type(4)));
typedef float f32x4 __attribute__((ext_vector_type(4)));

static __device__ inline f32x4 mfma16(half8 a, half8 b, f32x4 c) {
  return __builtin_amdgcn_mfma_f32_16x16x32_f16(a, b, c, 0, 0, 0);
}

static __device__ inline float fast_sigmoid(float x) {
  return __builtin_amdgcn_rcpf(1.f + __expf(-x));
}
static __device__ inline float fast_tanh(float x) {
  return 1.f - 2.f * __builtin_amdgcn_rcpf(__expf(2.f * x) + 1.f);
}

// A-fragment slot (element n,k) -> half index in a 4096-half fragment buffer
static __device__ inline int afrag_idx(int n, int k) {
  return ((((n >> 4) * 2 + (k >> 5)) * 64) + ((n & 15) | (((k >> 3) & 3) << 4))) * 8
         + (k & 7);
}

// ---------------------------------------------------------------------------
// E1 fused: x1[n,j] = eb1[j] + sum_k h[n,k]*ew1[j,k]; also x1f frag (fp16)
__global__ __launch_bounds__(256) void extract1(
    const float* __restrict__ h, const float* __restrict__ ew1,
    const float* __restrict__ eb1, float* __restrict__ x1,
    _Float16* __restrict__ x1f)
{
  int idx = blockIdx.x * 256 + threadIdx.x;   // 131072 total
  int n = idx >> 6, j = idx & 63;
  const float4* hr = (const float4*)(h + (size_t)n * 128);
  const float4* wr = (const float4*)(ew1 + (size_t)j * 128);
  float acc = eb1[j];
#pragma unroll
  for (int k4 = 0; k4 < 32; ++k4) {
    float4 a = hr[k4], w = wr[k4];
    acc += a.x * w.x + a.y * w.y + a.z * w.z + a.w * w.w;
  }
  x1[idx] = acc;
  int ks = n >> 5, nt = j >> 4;
  int l = (j & 15) | (((n >> 3) & 3) << 4);
  x1f[(((ks * 4 + nt) * 64) + l) * 8 + (n & 7)] = (_Float16)acc;
}

// ---------------------------------------------------------------------------
// E2 (MFMA): pooled = adj @ x1 (fp16 frags), deg = rowsum(adj) fp32;
//            x2 = pooled/deg + eps1*x1
__global__ __launch_bounds__(256) void extract2_mfma(
    const float* __restrict__ adj, const float* __restrict__ x1,
    const _Float16* __restrict__ x1f, const float* __restrict__ eps1,
    float* __restrict__ x2)
{
  const int n0 = blockIdx.x * 8;
  const int t = threadIdx.x;
  const int l = t & 63, wv = t >> 6;
  __shared__ __align__(16) _Float16 Abuf[4096];
  __shared__ float deg_l[8];

  for (int i = t; i < 4096; i += 256) Abuf[i] = (_Float16)0.f;

  const int row = t >> 5;
  const int kcol = (t & 31) * 8;
  const int s_my = (t & 31) >> 2;
  const int c_my = t & 3;

  float degp = 0.f;
  f32x4 acc = {0.f, 0.f, 0.f, 0.f};

  for (int kc = 0; kc < 8; ++kc) {
    __syncthreads();
    {
      const float* src = &adj[(size_t)(n0 + row) * 2048 + kc * 256 + kcol];
      float4 p0 = *(const float4*)src;
      float4 p1 = *(const float4*)(src + 4);
      degp += p0.x + p0.y + p0.z + p0.w + p1.x + p1.y + p1.z + p1.w;
      half8 v;
      v[0] = (_Float16)p0.x; v[1] = (_Float16)p0.y;
      v[2] = (_Float16)p0.z; v[3] = (_Float16)p0.w;
      v[4] = (_Float16)p1.x; v[5] = (_Float16)p1.y;
      v[6] = (_Float16)p1.z; v[7] = (_Float16)p1.w;
      *(half8*)&Abuf[(size_t)(s_my * 64 + (row | (c_my << 4))) * 8] = v;
    }
    __syncthreads();
#pragma unroll
    for (int s = 0; s < 8; ++s) {
      half8 A = *(half8*)&Abuf[(s * 64 + l) * 8];
      half8 B = *(const half8*)&x1f[(size_t)(((kc * 8 + s) * 4 + wv) * 64 + l) * 8];
      acc = mfma16(A, B, acc);
    }
  }

  for (int sh = 16; sh >= 1; sh >>= 1) degp += __shfl_down(degp, sh, 32);
  if ((t & 31) == 0) deg_l[row] = degp;
  __syncthreads();

  const float ep = eps1[0];
  int colc = wv * 16 + (l & 15);
  int r0 = (l >> 4) * 4;
  if (r0 < 8) {
#pragma unroll
    for (int q = 0; q < 4; ++q) {
      int r = r0 + q;
      float d = deg_l[r];
      d = (d < 1e-6f) ? 1.f : d;
      size_t off = (size_t)(n0 + r) * 64 + colc;
      x2[off] = acc[q] / d + ep * x1[off];
    }
  }
}

// ---------------------------------------------------------------------------
// E3a: partial BN sums over 32-row stripes -> psum/pqsum[64][64]
__global__ __launch_bounds__(256) void extract3a(
    const float* __restrict__ x2, float* __restrict__ psum,
    float* __restrict__ pqsum)
{
  int g = blockIdx.x;
  int t = threadIdx.x, j = t & 63, rg = t >> 6;
  __shared__ float sl[4][64], ql[4][64];
  float s = 0.f, q = 0.f;
  for (int r = g * 32 + rg; r < g * 32 + 32; r += 4) {
    float v = x2[(size_t)r * 64 + j];
    s += v; q += v * v;
  }
  sl[rg][j] = s; ql[rg][j] = q;
  __syncthreads();
  if (t < 64) {
    psum[g * 64 + t]  = sl[0][t] + sl[1][t] + sl[2][t] + sl[3][t];
    pqsum[g * 64 + t] = ql[0][t] + ql[1][t] + ql[2][t] + ql[3][t];
  }
}

__global__ void extract3b(
    const float* __restrict__ psum, const float* __restrict__ pqsum,
    const float* __restrict__ bnw, const float* __restrict__ bnb,
    float* __restrict__ scale, float* __restrict__ shift)
{
  int j = threadIdx.x;   // 64 threads
  float s = 0.f, q = 0.f;
  for (int g = 0; g < 64; ++g) { s += psum[g * 64 + j]; q += pqsum[g * 64 + j]; }
  float mean = s * (1.f / 2048.f);
  float var = q * (1.f / 2048.f) - mean * mean;
  float rstd = rsqrtf(var + 1e-5f);
  float sc = rstd * bnw[j];
  scale[j] = sc;
  shift[j] = bnb[j] - mean * sc;
}

// ---------------------------------------------------------------------------
// E4: xn = x2*scale+shift; feat = xn@ew2.T+eb2; fp = feat@wg+bg;
//     fplC (C-fragment layout, fp16)
__global__ __launch_bounds__(256) void extract4(
    const float* __restrict__ x2, const float* __restrict__ scale,
    const float* __restrict__ shift, const float* __restrict__ ew2,
    const float* __restrict__ eb2, const float* __restrict__ wg,
    const float* __restrict__ bg, const float* __restrict__ wl_w,
    const float* __restrict__ wl_b, _Float16* __restrict__ fplC)
{
  __shared__ float xn[4][64], ft[4][64], fp[4][64];
  int t = threadIdx.x, sub = t >> 6, o = t & 63;
  int n = blockIdx.x * 4 + sub;
  xn[sub][o] = x2[(size_t)n * 64 + o] * scale[o] + shift[o];
  __syncthreads();
  {
    float acc = eb2[o];
    for (int k = 0; k < 64; ++k) acc += xn[sub][k] * ew2[o * 64 + k];
    ft[sub][o] = acc;
  }
  __syncthreads();
  {
    float acc = bg[0];
    for (int k = 0; k < 64; ++k) acc += ft[sub][k] * wg[k * 64 + o];
    fp[sub][o] = acc;
  }
  __syncthreads();
  {
    float acc = wl_b[o];
    for (int k = 0; k < 64; ++k) acc += fp[sub][k] * wl_w[o * 128 + 64 + k];
    int tile = n >> 6, r = n & 63;
    int mt = r >> 4, qq = r & 3;
    int l = (o & 15) | (((r >> 2) & 3) << 4);
    fplC[(((tile * 4 + (o >> 4)) * 256) + mt * 64 + l) * 4 + qq] = (_Float16)acc;
  }
}

// ---------------------------------------------------------------------------
// Weight -> fp16 fragment arrays (k-map: kk = (l>>4)*8 + e).
__global__ __launch_bounds__(256) void prep_frags(
    const float* __restrict__ w1, const float* __restrict__ w2,
    const float* __restrict__ wl_w, _Float16* __restrict__ w1f,
    _Float16* __restrict__ w2f, _Float16* __restrict__ wlf)
{
  int idx = blockIdx.x * 256 + threadIdx.x;   // 16384 total
  int e = idx & 7, l = (idx >> 3) & 63;
  int kk = ((l >> 4) * 8) + e;
  if (idx < 8192) {
    int ks = (idx >> 9) & 1, nt = idx >> 10;  // nt 0..7
    int k = ks * 32 + kk;
    w1f[idx] = (_Float16)w1[(1 + k) * 128 + nt * 16 + (l & 15)];
  } else if (idx < 12288) {
    int i2 = idx - 8192;
    int ks = (i2 >> 9) & 1, nt = i2 >> 10;    // nt 0..3
    int k = ks * 32 + kk;
    w2f[i2] = (_Float16)w2[(1 + k) * 64 + nt * 16 + (l & 15)];
  } else {
    int i3 = idx - 12288;
    int ks = (i3 >> 9) & 1, nt = i3 >> 10;    // nt 0..3
    int k = ks * 32 + kk;
    wlf[i3] = (_Float16)wl_w[(nt * 16 + (l & 15)) * 128 + k];
  }
}

// ---------------------------------------------------------------------------
// Device-scope generation barrier. All 1024 blocks must be co-resident
// (guaranteed structurally: 256 thr, <=128 VGPR via launch_bounds, 32.5KB LDS
// -> 4 blocks/CU x 256 CU = 1024).
static __device__ inline void gridbar(unsigned* ctr, unsigned* gen, unsigned g) {
  __syncthreads();
  if (threadIdx.x == 0) {
    __threadfence();                       // L2 writeback (release)
    if (atomicAdd(ctr, 1u) == 1023u) {
      atomicExch(ctr, 0u);                 // reset for next use
      atomicExch(gen, g + 1u);             // release waiters
    } else {
      while (__hip_atomic_load(gen, __ATOMIC_RELAXED, __HIP_MEMORY_SCOPE_AGENT)
             == g)
        __builtin_amdgcn_s_sleep(16);
    }
    __threadfence();                       // invalidate (acquire)
  }
  __syncthreads();
}

// ---------------------------------------------------------------------------
// All 12 GRU steps, persistent. Block beta: tile = beta&31 (nodes [a,a+64)),
// batches bA = beta>>5 and bA+32 processed sequentially per step.
__global__ __launch_bounds__(256, 4) void gru_all(
    _Float16* __restrict__ h0, _Float16* __restrict__ h1,
    float* __restrict__ outF, const float* __restrict__ inputs,
    const float* __restrict__ w1, const float* __restrict__ b1,
    const float* __restrict__ w2, const float* __restrict__ b2,
    const _Float16* __restrict__ fplC, const _Float16* __restrict__ w1f,
    const _Float16* __restrict__ w2f, const _Float16* __restrict__ wlf,
    unsigned* __restrict__ bar)
{
  const int beta = blockIdx.x;
  const int tile = beta & 31;
  const int bA   = beta >> 5;        // 0..31
  const int a = tile * 64;
  const int t = threadIdx.x;
  const int l = t & 63, wv = t >> 6;
  const int halfBase = a >> 1;

  __shared__ __align__(16) _Float16 Asrc[4096];   // hs_src frags -> new frags
  __shared__ __align__(16) _Float16 A2f[4096];    // rh frags
  __shared__ __align__(16) _Float16 uF[4096];     // u gates (afrag layout)
  __shared__ __align__(16) _Float16 hsOwn[4096];  // own hs rows [64][64]
  __shared__ float xts[64], xto[64];

  // ---- persistent fragments / scalars (live across all 12 steps)
  half8 B1[2][2];
#pragma unroll
  for (int q = 0; q < 2; ++q)
#pragma unroll
    for (int ks = 0; ks < 2; ++ks)
      B1[q][ks] = *(const half8*)&w1f[((((2 * wv + q) * 2 + ks) * 64) + l) * 8];
  half8 B2a = *(const half8*)&w2f[(((wv * 2 + 0) * 64) + l) * 8];
  half8 B2b = *(const half8*)&w2f[(((wv * 2 + 1) * 64) + l) * 8];
  half8 B3a = *(const half8*)&wlf[(((wv * 2 + 0) * 64) + l) * 8];
  half8 B3b = *(const half8*)&wlf[(((wv * 2 + 1) * 64) + l) * 8];
  half4 fpl[4];
#pragma unroll
  for (int mt = 0; mt < 4; ++mt)
    fpl[mt] = *(const half4*)&fplC[(((tile * 4 + wv) * 256) + mt * 64 + l) * 4];
  const int colP2 = wv * 16 + (l & 15);
  const float b2c = b2[colP2], w2x = w2[colP2];
  float bcol[2], w1x[2];
#pragma unroll
  for (int q = 0; q < 2; ++q) {
    int col = (2 * wv + q) * 16 + (l & 15);
    bcol[q] = b1[col]; w1x[q] = w1[col];
  }
  const int bit = wv >> 1;   // P1 gate col >= 64 iff wv >= 2

  for (int step = 0; step < 12; ++step) {
    const int first = (step == 0);
    const _Float16* hsPrev = (step & 1) ? h0 : h1;
    _Float16* hsNext = (step & 1) ? h1 : h0;

    for (int u = 0; u < 2; ++u) {
      const int b = bA + u * 32;
      const float* xt = inputs + (size_t)(b * 12 + step) * 2048;
      const _Float16* hsb = hsPrev + (size_t)b * 131072;

      __syncthreads();   // LDS safe to overwrite (prev unit's P3 done)

      if (t < 64) {
        xto[t] = xt[a + t];
      } else if (t < 128) {
        int m = t - 64;
        int ns = (m < 32) ? (halfBase + m) : (1024 + halfBase + m - 32);
        xts[m] = xt[ns];
      }
      for (int i = t; i < 512; i += 256) {
        int m = i >> 3, k8 = i & 7;
        half8 v, vo;
        if (first) {
#pragma unroll
          for (int e = 0; e < 8; ++e) v[e] = (_Float16)0.f;
          vo = v;
        } else {
          int ns = (m < 32) ? (halfBase + m) : (1024 + halfBase + m - 32);
          v  = *(const half8*)&hsb[(size_t)ns * 64 + k8 * 8];
          vo = *(const half8*)&hsb[(size_t)(a + m) * 64 + k8 * 8];
        }
        int mt = m >> 4, ks = k8 >> 2, kc = k8 & 3;
        *(half8*)&Asrc[(((mt * 2 + ks) * 64) + ((m & 15) | (kc << 4))) * 8] = v;
        *(half8*)&hsOwn[i * 8] = vo;
      }
      __syncthreads();

      // ---- P1: gates = sigmoid(b1 + xt_src*w1row0 + hs_src @ w1);
      //      fused scatter: r -> A2f = r*hsOwn; u -> uF
#pragma unroll
      for (int mt = 0; mt < 4; ++mt) {
        half8 Aa = *(half8*)&Asrc[(((mt * 2 + 0) * 64) + l) * 8];
        half8 Ab = *(half8*)&Asrc[(((mt * 2 + 1) * 64) + l) * 8];
        int r0 = mt * 16 + (l >> 4) * 4;
#pragma unroll
        for (int q = 0; q < 2; ++q) {
          int col = (2 * wv + q) * 16 + (l & 15);
          f32x4 acc;
          acc[0] = bcol[q] + xts[r0 + 0] * w1x[q];
          acc[1] = bcol[q] + xts[r0 + 1] * w1x[q];
          acc[2] = bcol[q] + xts[r0 + 2] * w1x[q];
          acc[3] = bcol[q] + xts[r0 + 3] * w1x[q];
          acc = mfma16(Aa, B1[q][0], acc);
          acc = mfma16(Ab, B1[q][1], acc);
          const int k = col & 63;
#pragma unroll
          for (int qq = 0; qq < 4; ++qq) {
            float g = fast_sigmoid(acc[qq]);
            int m = r0 + qq;
            if (mt < 2) {
              int n = 2 * m + bit;
              float hf = (float)hsOwn[n * 64 + k];
              A2f[afrag_idx(n, k)] = (_Float16)(g * hf);
            } else {
              int n = 2 * (m - 32) + bit;
              uF[afrag_idx(n, k)] = (_Float16)g;
            }
          }
        }
      }
      __syncthreads();

      // ---- P2: c = tanh(b2 + xt_own*w2row0 + rh @ w2);
      //      fused: new = u*hsOwn + (1-u)*c -> Asrc
#pragma unroll
      for (int mt = 0; mt < 4; ++mt) {
        half8 Aa = *(half8*)&A2f[(((mt * 2 + 0) * 64) + l) * 8];
        half8 Ab = *(half8*)&A2f[(((mt * 2 + 1) * 64) + l) * 8];
        int r0 = mt * 16 + (l >> 4) * 4;
        f32x4 acc;
        acc[0] = b2c + xto[r0 + 0] * w2x;
        acc[1] = b2c + xto[r0 + 1] * w2x;
        acc[2] = b2c + xto[r0 + 2] * w2x;
        acc[3] = b2c + xto[r0 + 3] * w2x;
        acc = mfma16(Aa, B2a, acc);
        acc = mfma16(Ab, B2b, acc);
#pragma unroll
        for (int qq = 0; qq < 4; ++qq) {
          int row = r0 + qq;
          float cv = fast_tanh(acc[qq]);
          int idx3 = afrag_idx(row, colP2);
          float u2 = (float)uF[idx3];
          float hsv = (float)hsOwn[row * 64 + colP2];
          Asrc[idx3] = (_Float16)(u2 * hsv + (1.f - u2) * cv);
        }
      }
      __syncthreads();

      // ---- P3: out = fplC + new @ wlT
#pragma unroll
      for (int mt = 0; mt < 4; ++mt) {
        half8 Aa = *(half8*)&Asrc[(((mt * 2 + 0) * 64) + l) * 8];
        half8 Ab = *(half8*)&Asrc[(((mt * 2 + 1) * 64) + l) * 8];
        int r0 = mt * 16 + (l >> 4) * 4;
        f32x4 acc;
        acc[0] = (float)fpl[mt][0]; acc[1] = (float)fpl[mt][1];
        acc[2] = (float)fpl[mt][2]; acc[3] = (float)fpl[mt][3];
        acc = mfma16(Aa, B3a, acc);
        acc = mfma16(Ab, B3b, acc);
        if (step == 11) {
#pragma unroll
          for (int qq = 0; qq < 4; ++qq)
            outF[(size_t)b * 131072 + (size_t)(a + r0 + qq) * 64 + colP2] =
                acc[qq];
        } else {
#pragma unroll
          for (int qq = 0; qq < 4; ++qq)
            hsNext[(size_t)b * 131072 + (size_t)(a + r0 + qq) * 64 + colP2] =
                (_Float16)acc[qq];
        }
      }
    }
    if (step < 11) gridbar(bar, bar + 1, (unsigned)step);
  }
}

// ---------------------------------------------------------------------------
extern "C" void kernel_launch(void* const* d_in, const int* in_sizes, int n_in,
                              void* d_out, int out_size, void* d_ws, size_t ws_size,
                              hipStream_t stream) {
  const float* h      = (const float*)d_in[0];
  const float* adj    = (const float*)d_in[1];
  const float* inputs = (const float*)d_in[2];
  const float* ew1    = (const float*)d_in[3];
  const float* eb1    = (const float*)d_in[4];
  const float* ew2    = (const float*)d_in[5];
  const float* eb2    = (const float*)d_in[6];
  const float* eps1   = (const float*)d_in[7];
  const float* bnw    = (const float*)d_in[8];
  const float* bnb    = (const float*)d_in[9];
  const float* w1     = (const float*)d_in[10];
  const float* b1     = (const float*)d_in[11];
  const float* w2     = (const float*)d_in[12];
  const float* b2     = (const float*)d_in[13];
  const float* wg     = (const float*)d_in[14];
  const float* bg     = (const float*)d_in[15];
  const float* wl_w   = (const float*)d_in[16];
  const float* wl_b   = (const float*)d_in[17];

  char* ws = (char*)d_ws;

  // ws layout (bytes):
  //  [0, 16777216)           h0 (fp16 hs ping)
  //  [16777216, 33554432)    h1 (fp16 hs pong)
  //    aliased pre-GRU inside h1: x1 (131072 f32), x2 (131072 f32),
  //      x1f (131072 f16), psum (4096 f32), pqsum (4096 f32),
  //      scale (64 f32), shift (64 f32)
  //  [33554432, +262144)     fplC (131072 halfs)
  //  then w1f (8192 halfs), w2f (4096), wlf (4096), barrier (2 u32)
  _Float16* h0H = (_Float16*)ws;
  _Float16* h1H = (_Float16*)(ws + 16777216);
  float* x1    = (float*)h1H;
  float* x2    = x1 + 131072;
  _Float16* x1f = (_Float16*)(x2 + 131072);
  float* psum  = (float*)(x1f + 131072);
  float* pqsum = psum + 4096;
  float* scale = pqsum + 4096;
  float* shift = scale + 64;
  _Float16* fplC = (_Float16*)(ws + 33554432);
  _Float16* w1f  = fplC + 131072;
  _Float16* w2f  = w1f + 8192;
  _Float16* wlf  = w2f + 4096;
  unsigned* bar  = (unsigned*)(wlf + 4096);

  hipMemsetAsync(bar, 0, 8, stream);

  extract1<<<512, 256, 0, stream>>>(h, ew1, eb1, x1, x1f);
  extract2_mfma<<<256, 256, 0, stream>>>(adj, x1, x1f, eps1, x2);
  extract3a<<<64, 256, 0, stream>>>(x2, psum, pqsum);
  extract3b<<<1, 64, 0, stream>>>(psum, pqsum, bnw, bnb, scale, shift);
  extract4<<<512, 256, 0, stream>>>(x2, scale, shift, ew2, eb2, wg, bg,
                                    wl_w, wl_b, fplC);
  prep_frags<<<64, 256, 0, stream>>>(w1, w2, wl_w, w1f, w2f, wlf);

  gru_all<<<1024, 256, 0, stream>>>(h0H, h1H, (float*)d_out, inputs,
                                    w1, b1, w2, b2, fplC, w1f, w2f, wlf, bar);
}

// Round 8
// 312.225 us; speedup vs baseline: 6.0714x; 6.0714x over previous
//
#include <hip/hip_runtime.h>
#include <cstdint>

// Problem dims: N=2048, IN_DIM=128, HID=64, ENC=64, B=64, SEQ=12

typedef _Float16 half8 __attribute__((ext_vector_type(8)));
typedef _Float16 half4 __attribute__((ext_vector_type(4)));
typedef float f32x4 __attribute__((ext_vector_type(4)));

static __device__ inline f32x4 mfma16(half8 a, half8 b, f32x4 c) {
  return __builtin_amdgcn_mfma_f32_16x16x32_f16(a, b, c, 0, 0, 0);
}

static __device__ inline float fast_sigmoid(float x) {
  return __builtin_amdgcn_rcpf(1.f + __expf(-x));
}
static __device__ inline float fast_tanh(float x) {
  return 1.f - 2.f * __builtin_amdgcn_rcpf(__expf(2.f * x) + 1.f);
}

// LDS fragment-buffer slot swizzle: spreads slots {x,x+8,x+16,x+24} (which
// alias to one bank quad) across 4 disjoint bank quads. Bijective (XOR of
// bits 1-2 by untouched bits 3-4).
static __device__ inline int fswz(int slot) {
  return slot ^ (((slot >> 3) & 3) << 1);
}

// A-fragment slot (element n,k) -> half index (with slot swizzle)
static __device__ inline int afrag_idx(int n, int k) {
  int region = (n >> 4) * 2 + (k >> 5);
  int slot = (n & 15) | (((k >> 3) & 3) << 4);
  return (region * 64 + fswz(slot)) * 8 + (k & 7);
}

// hsOwn k-block swizzle selector: element (n,k) lives at n*64 + (k ^ hsw(n)).
// (((n>>2)^(n>>3))&3) is injective over row sets {c+8j} (P1) and the
// stride-4 row sets of P2 -> conflict-free 2B gathers.
static __device__ inline int hsw(int n) {
  return (((n >> 2) ^ (n >> 3)) & 3) << 4;
}

// ---------------------------------------------------------------------------
// E1 fused: x1[n,j] = eb1[j] + sum_k h[n,k]*ew1[j,k]; also x1f frag (fp16)
__global__ __launch_bounds__(256) void extract1(
    const float* __restrict__ h, const float* __restrict__ ew1,
    const float* __restrict__ eb1, float* __restrict__ x1,
    _Float16* __restrict__ x1f)
{
  int idx = blockIdx.x * 256 + threadIdx.x;   // 131072 total
  int n = idx >> 6, j = idx & 63;
  const float4* hr = (const float4*)(h + (size_t)n * 128);
  const float4* wr = (const float4*)(ew1 + (size_t)j * 128);
  float acc = eb1[j];
#pragma unroll
  for (int k4 = 0; k4 < 32; ++k4) {
    float4 a = hr[k4], w = wr[k4];
    acc += a.x * w.x + a.y * w.y + a.z * w.z + a.w * w.w;
  }
  x1[idx] = acc;
  int ks = n >> 5, nt = j >> 4;
  int l = (j & 15) | (((n >> 3) & 3) << 4);
  x1f[(((ks * 4 + nt) * 64) + l) * 8 + (n & 7)] = (_Float16)acc;
}

// ---------------------------------------------------------------------------
// E2 (MFMA): pooled = adj @ x1 (fp16 frags), deg = rowsum(adj) fp32;
//            x2 = pooled/deg + eps1*x1
__global__ __launch_bounds__(256) void extract2_mfma(
    const float* __restrict__ adj, const float* __restrict__ x1,
    const _Float16* __restrict__ x1f, const float* __restrict__ eps1,
    float* __restrict__ x2)
{
  const int n0 = blockIdx.x * 8;
  const int t = threadIdx.x;
  const int l = t & 63, wv = t >> 6;
  __shared__ __align__(16) _Float16 Abuf[4096];
  __shared__ float deg_l[8];

  for (int i = t; i < 4096; i += 256) Abuf[i] = (_Float16)0.f;

  const int row = t >> 5;
  const int kcol = (t & 31) * 8;
  const int s_my = (t & 31) >> 2;
  const int c_my = t & 3;

  float degp = 0.f;
  f32x4 acc = {0.f, 0.f, 0.f, 0.f};

  for (int kc = 0; kc < 8; ++kc) {
    __syncthreads();
    {
      const float* src = &adj[(size_t)(n0 + row) * 2048 + kc * 256 + kcol];
      float4 p0 = *(const float4*)src;
      float4 p1 = *(const float4*)(src + 4);
      degp += p0.x + p0.y + p0.z + p0.w + p1.x + p1.y + p1.z + p1.w;
      half8 v;
      v[0] = (_Float16)p0.x; v[1] = (_Float16)p0.y;
      v[2] = (_Float16)p0.z; v[3] = (_Float16)p0.w;
      v[4] = (_Float16)p1.x; v[5] = (_Float16)p1.y;
      v[6] = (_Float16)p1.z; v[7] = (_Float16)p1.w;
      *(half8*)&Abuf[(size_t)(s_my * 64 + (row | (c_my << 4))) * 8] = v;
    }
    __syncthreads();
#pragma unroll
    for (int s = 0; s < 8; ++s) {
      half8 A = *(half8*)&Abuf[(s * 64 + l) * 8];
      half8 B = *(const half8*)&x1f[(size_t)(((kc * 8 + s) * 4 + wv) * 64 + l) * 8];
      acc = mfma16(A, B, acc);
    }
  }

  for (int sh = 16; sh >= 1; sh >>= 1) degp += __shfl_down(degp, sh, 32);
  if ((t & 31) == 0) deg_l[row] = degp;
  __syncthreads();

  const float ep = eps1[0];
  int colc = wv * 16 + (l & 15);
  int r0 = (l >> 4) * 4;
  if (r0 < 8) {
#pragma unroll
    for (int q = 0; q < 4; ++q) {
      int r = r0 + q;
      float d = deg_l[r];
      d = (d < 1e-6f) ? 1.f : d;
      size_t off = (size_t)(n0 + r) * 64 + colc;
      x2[off] = acc[q] / d + ep * x1[off];
    }
  }
}

// ---------------------------------------------------------------------------
// E3a: partial BN sums over 32-row stripes -> psum/pqsum[64][64]
__global__ __launch_bounds__(256) void extract3a(
    const float* __restrict__ x2, float* __restrict__ psum,
    float* __restrict__ pqsum)
{
  int g = blockIdx.x;
  int t = threadIdx.x, j = t & 63, rg = t >> 6;
  __shared__ float sl[4][64], ql[4][64];
  float s = 0.f, q = 0.f;
  for (int r = g * 32 + rg; r < g * 32 + 32; r += 4) {
    float v = x2[(size_t)r * 64 + j];
    s += v; q += v * v;
  }
  sl[rg][j] = s; ql[rg][j] = q;
  __syncthreads();
  if (t < 64) {
    psum[g * 64 + t]  = sl[0][t] + sl[1][t] + sl[2][t] + sl[3][t];
    pqsum[g * 64 + t] = ql[0][t] + ql[1][t] + ql[2][t] + ql[3][t];
  }
}

__global__ void extract3b(
    const float* __restrict__ psum, const float* __restrict__ pqsum,
    const float* __restrict__ bnw, const float* __restrict__ bnb,
    float* __restrict__ scale, float* __restrict__ shift)
{
  int j = threadIdx.x;   // 64 threads
  float s = 0.f, q = 0.f;
  for (int g = 0; g < 64; ++g) { s += psum[g * 64 + j]; q += pqsum[g * 64 + j]; }
  float mean = s * (1.f / 2048.f);
  float var = q * (1.f / 2048.f) - mean * mean;
  float rstd = rsqrtf(var + 1e-5f);
  float sc = rstd * bnw[j];
  scale[j] = sc;
  shift[j] = bnb[j] - mean * sc;
}

// ---------------------------------------------------------------------------
// E4: xn = x2*scale+shift; feat = xn@ew2.T+eb2; fp = feat@wg+bg;
//     fplC (C-fragment layout, fp16)
__global__ __launch_bounds__(256) void extract4(
    const float* __restrict__ x2, const float* __restrict__ scale,
    const float* __restrict__ shift, const float* __restrict__ ew2,
    const float* __restrict__ eb2, const float* __restrict__ wg,
    const float* __restrict__ bg, const float* __restrict__ wl_w,
    const float* __restrict__ wl_b, _Float16* __restrict__ fplC)
{
  __shared__ float xn[4][64], ft[4][64], fp[4][64];
  int t = threadIdx.x, sub = t >> 6, o = t & 63;
  int n = blockIdx.x * 4 + sub;
  xn[sub][o] = x2[(size_t)n * 64 + o] * scale[o] + shift[o];
  __syncthreads();
  {
    float acc = eb2[o];
    for (int k = 0; k < 64; ++k) acc += xn[sub][k] * ew2[o * 64 + k];
    ft[sub][o] = acc;
  }
  __syncthreads();
  {
    float acc = bg[0];
    for (int k = 0; k < 64; ++k) acc += ft[sub][k] * wg[k * 64 + o];
    fp[sub][o] = acc;
  }
  __syncthreads();
  {
    float acc = wl_b[o];
    for (int k = 0; k < 64; ++k) acc += fp[sub][k] * wl_w[o * 128 + 64 + k];
    int tile = n >> 6, r = n & 63;
    int mt = r >> 4, qq = r & 3;
    int l = (o & 15) | (((r >> 2) & 3) << 4);
    fplC[(((tile * 4 + (o >> 4)) * 256) + mt * 64 + l) * 4 + qq] = (_Float16)acc;
  }
}

// ---------------------------------------------------------------------------
// Weight -> fp16 fragment arrays (k-map: kk = (l>>4)*8 + e).
__global__ __launch_bounds__(256) void prep_frags(
    const float* __restrict__ w1, const float* __restrict__ w2,
    const float* __restrict__ wl_w, _Float16* __restrict__ w1f,
    _Float16* __restrict__ w2f, _Float16* __restrict__ wlf)
{
  int idx = blockIdx.x * 256 + threadIdx.x;   // 16384 total
  int e = idx & 7, l = (idx >> 3) & 63;
  int kk = ((l >> 4) * 8) + e;
  if (idx < 8192) {
    int ks = (idx >> 9) & 1, nt = idx >> 10;  // nt 0..7
    int k = ks * 32 + kk;
    w1f[idx] = (_Float16)w1[(1 + k) * 128 + nt * 16 + (l & 15)];
  } else if (idx < 12288) {
    int i2 = idx - 8192;
    int ks = (i2 >> 9) & 1, nt = i2 >> 10;    // nt 0..3
    int k = ks * 32 + kk;
    w2f[i2] = (_Float16)w2[(1 + k) * 64 + nt * 16 + (l & 15)];
  } else {
    int i3 = idx - 12288;
    int ks = (i3 >> 9) & 1, nt = i3 >> 10;    // nt 0..3
    int k = ks * 32 + kk;
    wlf[i3] = (_Float16)wl_w[(nt * 16 + (l & 15)) * 128 + k];
  }
}

// ---------------------------------------------------------------------------
// One GRU step, fp16 MFMA, fp16 hs state, 3-barrier structure, LDS-swizzled.
// Block: batch b (blockIdx.y), nodes [a, a+64). 256 threads = 4 waves.
__global__ __launch_bounds__(256, 4) void gru_step(
    const _Float16* __restrict__ hs_in, void* __restrict__ hs_out_v,
    int outF32, const float* __restrict__ inputs, int tstep, int first,
    const float* __restrict__ w1, const float* __restrict__ b1,
    const float* __restrict__ w2, const float* __restrict__ b2,
    const _Float16* __restrict__ fplC, const _Float16* __restrict__ w1f,
    const _Float16* __restrict__ w2f, const _Float16* __restrict__ wlf)
{
  const int b = blockIdx.y;
  const int a = blockIdx.x * 64;
  const int t = threadIdx.x;
  const int l = t & 63, wv = t >> 6;
  const int lsw = fswz(l);           // physical slot for logical lane slot l
  const int halfBase = a >> 1;

  __shared__ __align__(16) _Float16 Asrc[4096];   // hs_src frags -> new frags
  __shared__ __align__(16) _Float16 A2f[4096];    // rh frags
  __shared__ __align__(16) _Float16 uF[4096];     // u gates (afrag layout)
  __shared__ __align__(16) _Float16 hsOwn[4096];  // own hs rows, k-swizzled
  __shared__ float xts[64], xto[64];

  const float* xt  = inputs + (size_t)(b * 12 + tstep) * 2048;
  const _Float16* hsb = hs_in + (size_t)b * 131072;

  if (t < 64) {
    xto[t] = xt[a + t];
  } else if (t < 128) {
    int m = t - 64;
    int ns = (m < 32) ? (halfBase + m) : (1024 + halfBase + m - 32);
    xts[m] = xt[ns];
  }

  // ---- stage hsOwn (k-swizzled) + Asrc = hs_src fp16 frags (slot-swizzled)
  for (int i = t; i < 512; i += 256) {
    int m = i >> 3, k8 = i & 7;
    half8 v, vo;
    if (first) {
#pragma unroll
      for (int e = 0; e < 8; ++e) v[e] = (_Float16)0.f;
      vo = v;
    } else {
      int ns = (m < 32) ? (halfBase + m) : (1024 + halfBase + m - 32);
      v  = *(const half8*)&hsb[(size_t)ns * 64 + k8 * 8];
      vo = *(const half8*)&hsb[(size_t)(a + m) * 64 + k8 * 8];
    }
    int mt = m >> 4, ks = k8 >> 2, kc = k8 & 3;
    *(half8*)&Asrc[(((mt * 2 + ks) * 64) + fswz((m & 15) | (kc << 4))) * 8] = v;
    *(half8*)&hsOwn[m * 64 + ((k8 * 8) ^ hsw(m))] = vo;
  }
  __syncthreads();

  // ---- Phase 1: gates = sigmoid(b1 + xt_src*w1row0 + hs_src @ w1);
  //      fused scatter: r -> A2f = r*hsOwn; u -> uF
  {
    half8 B1[2][2];
#pragma unroll
    for (int q = 0; q < 2; ++q)
#pragma unroll
      for (int ks = 0; ks < 2; ++ks)
        B1[q][ks] = *(const half8*)&w1f[((((2 * wv + q) * 2 + ks) * 64) + l) * 8];
    const int bit = (wv >> 1);   // gate col >= 64 iff wv >= 2
#pragma unroll
    for (int mt = 0; mt < 4; ++mt) {
      half8 Aa = *(half8*)&Asrc[(((mt * 2 + 0) * 64) + lsw) * 8];
      half8 Ab = *(half8*)&Asrc[(((mt * 2 + 1) * 64) + lsw) * 8];
      int r0 = mt * 16 + (l >> 4) * 4;
#pragma unroll
      for (int q = 0; q < 2; ++q) {
        int col = (2 * wv + q) * 16 + (l & 15);
        float bcol = b1[col], w1x = w1[col];
        f32x4 acc;
        acc[0] = bcol + xts[r0 + 0] * w1x;
        acc[1] = bcol + xts[r0 + 1] * w1x;
        acc[2] = bcol + xts[r0 + 2] * w1x;
        acc[3] = bcol + xts[r0 + 3] * w1x;
        acc = mfma16(Aa, B1[q][0], acc);
        acc = mfma16(Ab, B1[q][1], acc);
        const int k = col & 63;
#pragma unroll
        for (int qq = 0; qq < 4; ++qq) {
          float g = fast_sigmoid(acc[qq]);
          int m = r0 + qq;
          if (mt < 2) {          // r rows (m < 32)
            int n = 2 * m + bit;
            float hf = (float)hsOwn[n * 64 + (k ^ hsw(n))];
            A2f[afrag_idx(n, k)] = (_Float16)(g * hf);
          } else {               // u rows (m >= 32)
            int n = 2 * (m - 32) + bit;
            uF[afrag_idx(n, k)] = (_Float16)g;
          }
        }
      }
    }
  }
  __syncthreads();

  // ---- Phase 2: c = tanh(b2 + xt_own*w2row0 + rh @ w2);
  //      fused: new = u*hsOwn + (1-u)*c -> Asrc
  {
    half8 B2a = *(const half8*)&w2f[(((wv * 2 + 0) * 64) + l) * 8];
    half8 B2b = *(const half8*)&w2f[(((wv * 2 + 1) * 64) + l) * 8];
    int col = wv * 16 + (l & 15);
    float b2c = b2[col], w2x = w2[col];
#pragma unroll
    for (int mt = 0; mt < 4; ++mt) {
      half8 Aa = *(half8*)&A2f[(((mt * 2 + 0) * 64) + lsw) * 8];
      half8 Ab = *(half8*)&A2f[(((mt * 2 + 1) * 64) + lsw) * 8];
      int r0 = mt * 16 + (l >> 4) * 4;
      f32x4 acc;
      acc[0] = b2c + xto[r0 + 0] * w2x;
      acc[1] = b2c + xto[r0 + 1] * w2x;
      acc[2] = b2c + xto[r0 + 2] * w2x;
      acc[3] = b2c + xto[r0 + 3] * w2x;
      acc = mfma16(Aa, B2a, acc);
      acc = mfma16(Ab, B2b, acc);
#pragma unroll
      for (int qq = 0; qq < 4; ++qq) {
        int row = r0 + qq;
        float cv = fast_tanh(acc[qq]);
        int idx3 = afrag_idx(row, col);
        float u2 = (float)uF[idx3];
        float hsv = (float)hsOwn[row * 64 + (col ^ hsw(row))];
        Asrc[idx3] = (_Float16)(u2 * hsv + (1.f - u2) * cv);
      }
    }
  }
  __syncthreads();

  // ---- Phase 3: out = fplC + new @ wlT
  {
    half8 B3a = *(const half8*)&wlf[(((wv * 2 + 0) * 64) + l) * 8];
    half8 B3b = *(const half8*)&wlf[(((wv * 2 + 1) * 64) + l) * 8];
    int col = wv * 16 + (l & 15);
    const int tile = a >> 6;
#pragma unroll
    for (int mt = 0; mt < 4; ++mt) {
      half8 Aa = *(half8*)&Asrc[(((mt * 2 + 0) * 64) + lsw) * 8];
      half8 Ab = *(half8*)&Asrc[(((mt * 2 + 1) * 64) + lsw) * 8];
      int r0 = mt * 16 + (l >> 4) * 4;
      half4 f4 = *(const half4*)&fplC[(((tile * 4 + wv) * 256) + mt * 64 + l) * 4];
      f32x4 acc;
      acc[0] = (float)f4[0]; acc[1] = (float)f4[1];
      acc[2] = (float)f4[2]; acc[3] = (float)f4[3];
      acc = mfma16(Aa, B3a, acc);
      acc = mfma16(Ab, B3b, acc);
      if (outF32) {
        float* outp = (float*)hs_out_v;
#pragma unroll
        for (int qq = 0; qq < 4; ++qq)
          outp[(size_t)b * 131072 + (size_t)(a + r0 + qq) * 64 + col] = acc[qq];
      } else {
        _Float16* outp = (_Float16*)hs_out_v;
#pragma unroll
        for (int qq = 0; qq < 4; ++qq)
          outp[(size_t)b * 131072 + (size_t)(a + r0 + qq) * 64 + col] =
              (_Float16)acc[qq];
      }
    }
  }
}

// ---------------------------------------------------------------------------
extern "C" void kernel_launch(void* const* d_in, const int* in_sizes, int n_in,
                              void* d_out, int out_size, void* d_ws, size_t ws_size,
                              hipStream_t stream) {
  const float* h      = (const float*)d_in[0];
  const float* adj    = (const float*)d_in[1];
  const float* inputs = (const float*)d_in[2];
  const float* ew1    = (const float*)d_in[3];
  const float* eb1    = (const float*)d_in[4];
  const float* ew2    = (const float*)d_in[5];
  const float* eb2    = (const float*)d_in[6];
  const float* eps1   = (const float*)d_in[7];
  const float* bnw    = (const float*)d_in[8];
  const float* bnb    = (const float*)d_in[9];
  const float* w1     = (const float*)d_in[10];
  const float* b1     = (const float*)d_in[11];
  const float* w2     = (const float*)d_in[12];
  const float* b2     = (const float*)d_in[13];
  const float* wg     = (const float*)d_in[14];
  const float* bg     = (const float*)d_in[15];
  const float* wl_w   = (const float*)d_in[16];
  const float* wl_b   = (const float*)d_in[17];

  char* ws = (char*)d_ws;

  // ws layout (bytes):
  //  [0, 16777216)           h0 (fp16 hs ping)
  //  [16777216, 33554432)    h1 (fp16 hs pong)
  //    aliased pre-GRU inside h1: x1 (131072 f32), x2 (131072 f32),
  //      x1f (131072 f16), psum (4096 f32), pqsum (4096 f32),
  //      scale (64 f32), shift (64 f32)
  //  [33554432, +262144)     fplC (131072 halfs)
  //  then w1f (8192 halfs), w2f (4096), wlf (4096)
  _Float16* h0H = (_Float16*)ws;
  _Float16* h1H = (_Float16*)(ws + 16777216);
  float* x1    = (float*)h1H;
  float* x2    = x1 + 131072;
  _Float16* x1f = (_Float16*)(x2 + 131072);
  float* psum  = (float*)(x1f + 131072);
  float* pqsum = psum + 4096;
  float* scale = pqsum + 4096;
  float* shift = scale + 64;
  _Float16* fplC = (_Float16*)(ws + 33554432);
  _Float16* w1f  = fplC + 131072;
  _Float16* w2f  = w1f + 8192;
  _Float16* wlf  = w2f + 4096;

  extract1<<<512, 256, 0, stream>>>(h, ew1, eb1, x1, x1f);
  extract2_mfma<<<256, 256, 0, stream>>>(adj, x1, x1f, eps1, x2);
  extract3a<<<64, 256, 0, stream>>>(x2, psum, pqsum);
  extract3b<<<1, 64, 0, stream>>>(psum, pqsum, bnw, bnb, scale, shift);
  extract4<<<512, 256, 0, stream>>>(x2, scale, shift, ew2, eb2, wg, bg,
                                    wl_w, wl_b, fplC);
  prep_frags<<<64, 256, 0, stream>>>(w1, w2, wl_w, w1f, w2f, wlf);

  dim3 grid(32, 64);
  for (int t = 0; t < 12; ++t) {
    const _Float16* ibuf = (t & 1) ? h0H : h1H;   // t=0 ignores (first=1)
    void* obuf; int of32 = 0;
    if (t == 11) { obuf = d_out; of32 = 1; }
    else obuf = (t & 1) ? (void*)h1H : (void*)h0H;
    gru_step<<<grid, 256, 0, stream>>>(ibuf, obuf, of32, inputs, t,
                                       (t == 0) ? 1 : 0,
                                       w1, b1, w2, b2, fplC, w1f, w2f, wlf);
  }
}

// Round 9
// 251.082 us; speedup vs baseline: 7.5498x; 1.2435x over previous
//
#include <hip/hip_runtime.h>
#include <cstdint>

// Problem dims: N=2048, IN_DIM=128, HID=64, ENC=64, B=64, SEQ=12

typedef _Float16 half8 __attribute__((ext_vector_type(8)));
typedef _Float16 half4 __attribute__((ext_vector_type(4)));
typedef float f32x4 __attribute__((ext_vector_type(4)));

static __device__ inline f32x4 mfma16(half8 a, half8 b, f32x4 c) {
  return __builtin_amdgcn_mfma_f32_16x16x32_f16(a, b, c, 0, 0, 0);
}

static __device__ inline float fast_sigmoid(float x) {
  return __builtin_amdgcn_rcpf(1.f + __expf(-x));
}
static __device__ inline float fast_tanh(float x) {
  return 1.f - 2.f * __builtin_amdgcn_rcpf(__expf(2.f * x) + 1.f);
}

// A/B-fragment half-index for element (n, k), plain layout.
// region = (n>>4)*2 + (k>>5); slot = (n&15)|(((k>>3)&3)<<4); elem = k&7.
static __device__ inline int afr4(int n, int k) {
  return ((n >> 4) * 2 + (k >> 5)) * 512 +
         (((n & 15) | (((k >> 3) & 3) << 4)) * 8) + (k & 7);
}

// hsOwn with 8-half-block XOR swizzle: element (n,k) at
// n*64 + ((k>>3)^((n>>1)&7))*8 + (k&7). Keeps 16B staging writes intact,
// spreads the P1 gather (n stride 2) and P2 gather (n stride 1) across banks.
static __device__ inline int hso4(int n, int k) {
  return n * 64 + (((k >> 3) ^ ((n >> 1) & 7)) * 8) + (k & 7);
}

// ---------------------------------------------------------------------------
// E1 fused: x1[n,j] = eb1[j] + sum_k h[n,k]*ew1[j,k]; also x1f frag (fp16)
__global__ __launch_bounds__(256) void extract1(
    const float* __restrict__ h, const float* __restrict__ ew1,
    const float* __restrict__ eb1, float* __restrict__ x1,
    _Float16* __restrict__ x1f)
{
  int idx = blockIdx.x * 256 + threadIdx.x;   // 131072 total
  int n = idx >> 6, j = idx & 63;
  const float4* hr = (const float4*)(h + (size_t)n * 128);
  const float4* wr = (const float4*)(ew1 + (size_t)j * 128);
  float acc = eb1[j];
#pragma unroll
  for (int k4 = 0; k4 < 32; ++k4) {
    float4 a = hr[k4], w = wr[k4];
    acc += a.x * w.x + a.y * w.y + a.z * w.z + a.w * w.w;
  }
  x1[idx] = acc;
  int ks = n >> 5, nt = j >> 4;
  int l = (j & 15) | (((n >> 3) & 3) << 4);
  x1f[(((ks * 4 + nt) * 64) + l) * 8 + (n & 7)] = (_Float16)acc;
}

// ---------------------------------------------------------------------------
// E2 (MFMA): pooled = adj @ x1 (fp16 frags), deg = rowsum(adj) fp32;
//            x2 = pooled/deg + eps1*x1
__global__ __launch_bounds__(256) void extract2_mfma(
    const float* __restrict__ adj, const float* __restrict__ x1,
    const _Float16* __restrict__ x1f, const float* __restrict__ eps1,
    float* __restrict__ x2)
{
  const int n0 = blockIdx.x * 8;
  const int t = threadIdx.x;
  const int l = t & 63, wv = t >> 6;
  __shared__ __align__(16) _Float16 Abuf[4096];
  __shared__ float deg_l[8];

  for (int i = t; i < 4096; i += 256) Abuf[i] = (_Float16)0.f;

  const int row = t >> 5;
  const int kcol = (t & 31) * 8;
  const int s_my = (t & 31) >> 2;
  const int c_my = t & 3;

  float degp = 0.f;
  f32x4 acc = {0.f, 0.f, 0.f, 0.f};

  for (int kc = 0; kc < 8; ++kc) {
    __syncthreads();
    {
      const float* src = &adj[(size_t)(n0 + row) * 2048 + kc * 256 + kcol];
      float4 p0 = *(const float4*)src;
      float4 p1 = *(const float4*)(src + 4);
      degp += p0.x + p0.y + p0.z + p0.w + p1.x + p1.y + p1.z + p1.w;
      half8 v;
      v[0] = (_Float16)p0.x; v[1] = (_Float16)p0.y;
      v[2] = (_Float16)p0.z; v[3] = (_Float16)p0.w;
      v[4] = (_Float16)p1.x; v[5] = (_Float16)p1.y;
      v[6] = (_Float16)p1.z; v[7] = (_Float16)p1.w;
      *(half8*)&Abuf[(size_t)(s_my * 64 + (row | (c_my << 4))) * 8] = v;
    }
    __syncthreads();
#pragma unroll
    for (int s = 0; s < 8; ++s) {
      half8 A = *(half8*)&Abuf[(s * 64 + l) * 8];
      half8 B = *(const half8*)&x1f[(size_t)(((kc * 8 + s) * 4 + wv) * 64 + l) * 8];
      acc = mfma16(A, B, acc);
    }
  }

  for (int sh = 16; sh >= 1; sh >>= 1) degp += __shfl_down(degp, sh, 32);
  if ((t & 31) == 0) deg_l[row] = degp;
  __syncthreads();

  const float ep = eps1[0];
  int colc = wv * 16 + (l & 15);
  int r0 = (l >> 4) * 4;
  if (r0 < 8) {
#pragma unroll
    for (int q = 0; q < 4; ++q) {
      int r = r0 + q;
      float d = deg_l[r];
      d = (d < 1e-6f) ? 1.f : d;
      size_t off = (size_t)(n0 + r) * 64 + colc;
      x2[off] = acc[q] / d + ep * x1[off];
    }
  }
}

// ---------------------------------------------------------------------------
// E3a: partial BN sums over 32-row stripes -> psum/pqsum[64][64]
__global__ __launch_bounds__(256) void extract3a(
    const float* __restrict__ x2, float* __restrict__ psum,
    float* __restrict__ pqsum)
{
  int g = blockIdx.x;
  int t = threadIdx.x, j = t & 63, rg = t >> 6;
  __shared__ float sl[4][64], ql[4][64];
  float s = 0.f, q = 0.f;
  for (int r = g * 32 + rg; r < g * 32 + 32; r += 4) {
    float v = x2[(size_t)r * 64 + j];
    s += v; q += v * v;
  }
  sl[rg][j] = s; ql[rg][j] = q;
  __syncthreads();
  if (t < 64) {
    psum[g * 64 + t]  = sl[0][t] + sl[1][t] + sl[2][t] + sl[3][t];
    pqsum[g * 64 + t] = ql[0][t] + ql[1][t] + ql[2][t] + ql[3][t];
  }
}

__global__ void extract3b(
    const float* __restrict__ psum, const float* __restrict__ pqsum,
    const float* __restrict__ bnw, const float* __restrict__ bnb,
    float* __restrict__ scale, float* __restrict__ shift)
{
  int j = threadIdx.x;   // 64 threads
  float s = 0.f, q = 0.f;
  for (int g = 0; g < 64; ++g) { s += psum[g * 64 + j]; q += pqsum[g * 64 + j]; }
  float mean = s * (1.f / 2048.f);
  float var = q * (1.f / 2048.f) - mean * mean;
  float rstd = rsqrtf(var + 1e-5f);
  float sc = rstd * bnw[j];
  scale[j] = sc;
  shift[j] = bnb[j] - mean * sc;
}

// ---------------------------------------------------------------------------
// E4: xn = x2*scale+shift; feat = xn@ew2.T+eb2; fp = feat@wg+bg;
//     fplC in SWAPPED C' layout: C'[row=o][col=n]:
//     fplC[((tile*4 + o>>4)*256 + ((n>>4)&3)*64 + ((n&15)|(((o>>2)&3)<<4)))*4 + (o&3)]
__global__ __launch_bounds__(256) void extract4(
    const float* __restrict__ x2, const float* __restrict__ scale,
    const float* __restrict__ shift, const float* __restrict__ ew2,
    const float* __restrict__ eb2, const float* __restrict__ wg,
    const float* __restrict__ bg, const float* __restrict__ wl_w,
    const float* __restrict__ wl_b, _Float16* __restrict__ fplC)
{
  __shared__ float xn[4][64], ft[4][64], fp[4][64];
  int t = threadIdx.x, sub = t >> 6, o = t & 63;
  int n = blockIdx.x * 4 + sub;
  xn[sub][o] = x2[(size_t)n * 64 + o] * scale[o] + shift[o];
  __syncthreads();
  {
    float acc = eb2[o];
    for (int k = 0; k < 64; ++k) acc += xn[sub][k] * ew2[o * 64 + k];
    ft[sub][o] = acc;
  }
  __syncthreads();
  {
    float acc = bg[0];
    for (int k = 0; k < 64; ++k) acc += ft[sub][k] * wg[k * 64 + o];
    fp[sub][o] = acc;
  }
  __syncthreads();
  {
    float acc = wl_b[o];
    for (int k = 0; k < 64; ++k) acc += fp[sub][k] * wl_w[o * 128 + 64 + k];
    int tile = n >> 6;
    int ntp = (n >> 4) & 3;
    int lane = (n & 15) | (((o >> 2) & 3) << 4);
    fplC[(((tile * 4 + (o >> 4)) * 256) + ntp * 64 + lane) * 4 + (o & 3)] =
        (_Float16)acc;
  }
}

// ---------------------------------------------------------------------------
// Weight -> fp16 fragment arrays (lane map: row/col = l&15, k = ks*32+(l>>4)*8+e)
__global__ __launch_bounds__(256) void prep_frags(
    const float* __restrict__ w1, const float* __restrict__ w2,
    const float* __restrict__ wl_w, _Float16* __restrict__ w1f,
    _Float16* __restrict__ w2f, _Float16* __restrict__ wlf)
{
  int idx = blockIdx.x * 256 + threadIdx.x;   // 16384 total
  int e = idx & 7, l = (idx >> 3) & 63;
  int kk = ((l >> 4) * 8) + e;
  if (idx < 8192) {
    int ks = (idx >> 9) & 1, nt = idx >> 10;  // nt 0..7
    int k = ks * 32 + kk;
    w1f[idx] = (_Float16)w1[(1 + k) * 128 + nt * 16 + (l & 15)];
  } else if (idx < 12288) {
    int i2 = idx - 8192;
    int ks = (i2 >> 9) & 1, nt = i2 >> 10;    // nt 0..3
    int k = ks * 32 + kk;
    w2f[i2] = (_Float16)w2[(1 + k) * 64 + nt * 16 + (l & 15)];
  } else {
    int i3 = idx - 12288;
    int ks = (i3 >> 9) & 1, nt = i3 >> 10;    // nt 0..3
    int k = ks * 32 + kk;
    wlf[i3] = (_Float16)wl_w[(nt * 16 + (l & 15)) * 128 + k];
  }
}

// ---------------------------------------------------------------------------
// One GRU step, SWAPPED-operand MFMAs (C' = [out-col][node]) so every
// epilogue is half4-vectorized. Block: tile=blockIdx.x (nodes [a,a+64)),
// batches bA=blockIdx.y and bA+32 sequentially. 256 threads = 4 waves.
__global__ __launch_bounds__(256, 4) void gru_step(
    const _Float16* __restrict__ hs_in, void* __restrict__ hs_out_v,
    int outF32, const float* __restrict__ inputs, int tstep, int first,
    const float* __restrict__ w1, const float* __restrict__ b1,
    const float* __restrict__ w2, const float* __restrict__ b2,
    const _Float16* __restrict__ fplC, const _Float16* __restrict__ w1f,
    const _Float16* __restrict__ w2f, const _Float16* __restrict__ wlf)
{
  const int tile = blockIdx.x;
  const int bA   = blockIdx.y;      // 0..31
  const int a = tile * 64;
  const int t = threadIdx.x;
  const int l = t & 63, wv = t >> 6;
  const int lq = l >> 4, li = l & 15;
  const int halfBase = a >> 1;

  __shared__ __align__(16) _Float16 Asrc[4096];   // hs_src frags -> new frags
  __shared__ __align__(16) _Float16 A2f[4096];    // rh frags
  __shared__ __align__(16) _Float16 uF[4096];     // u gates (frag layout)
  __shared__ __align__(16) _Float16 hsOwn[4096];  // own hs, k8-swizzled
  __shared__ float xts[64], xto[64];

  // ---- persistent per-kernel register loads (shared by both batch units)
  half8 Aw1[2][2];
#pragma unroll
  for (int q = 0; q < 2; ++q)
#pragma unroll
    for (int ks = 0; ks < 2; ++ks)
      Aw1[q][ks] = *(const half8*)&w1f[((((2 * wv + q) * 2 + ks) * 64) + l) * 8];
  half8 Aw2[2], Awl[2];
#pragma unroll
  for (int ks = 0; ks < 2; ++ks) {
    Aw2[ks] = *(const half8*)&w2f[(((wv * 2 + ks) * 64) + l) * 8];
    Awl[ks] = *(const half8*)&wlf[(((wv * 2 + ks) * 64) + l) * 8];
  }
  half4 fpl4[4];
#pragma unroll
  for (int nt = 0; nt < 4; ++nt)
    fpl4[nt] = *(const half4*)&fplC[(((tile * 4 + wv) * 256) + nt * 64 + l) * 4];
  float bjR[2][4], w1xR[2][4];
#pragma unroll
  for (int q = 0; q < 2; ++q)
#pragma unroll
    for (int qq = 0; qq < 4; ++qq) {
      int j = (2 * wv + q) * 16 + lq * 4 + qq;
      bjR[q][qq] = b1[j];
      w1xR[q][qq] = w1[j];          // w1 row 0
    }
  float b2R[4], w2xR[4];
#pragma unroll
  for (int qq = 0; qq < 4; ++qq) {
    int o = wv * 16 + lq * 4 + qq;
    b2R[qq] = b2[o];
    w2xR[qq] = w2[o];               // w2 row 0
  }
  const int bit = wv >> 1;          // gate col j>=64 iff wv>=2

  for (int uu = 0; uu < 2; ++uu) {
    const int b = bA + uu * 32;
    const float* xt = inputs + (size_t)(b * 12 + tstep) * 2048;
    const _Float16* hsb = hs_in + (size_t)b * 131072;

    __syncthreads();   // LDS safe to overwrite

    if (t < 64) {
      xto[t] = xt[a + t];
    } else if (t < 128) {
      int m = t - 64;
      int ns = (m < 32) ? (halfBase + m) : (1024 + halfBase + m - 32);
      xts[m] = xt[ns];
    }
    for (int i = t; i < 512; i += 256) {
      int m = i >> 3, k8 = i & 7;
      half8 v, vo;
      if (first) {
#pragma unroll
        for (int e = 0; e < 8; ++e) v[e] = (_Float16)0.f;
        vo = v;
      } else {
        int ns = (m < 32) ? (halfBase + m) : (1024 + halfBase + m - 32);
        v  = *(const half8*)&hsb[(size_t)ns * 64 + k8 * 8];
        vo = *(const half8*)&hsb[(size_t)(a + m) * 64 + k8 * 8];
      }
      int mt = m >> 4, ks = k8 >> 2, kc = k8 & 3;
      *(half8*)&Asrc[(((mt * 2 + ks) * 64) + ((m & 15) | (kc << 4))) * 8] = v;
      *(half8*)&hsOwn[m * 64 + ((k8 ^ ((m >> 1) & 7)) * 8)] = vo;
    }
    __syncthreads();

    float xtsR[4], xtoR[4];
#pragma unroll
    for (int nt = 0; nt < 4; ++nt) {
      xtsR[nt] = xts[nt * 16 + li];
      xtoR[nt] = xto[nt * 16 + li];
    }

    // ---- P1 (swapped): C'[j][m] = w1^T x hs_src. Thread: 4 consecutive k
    //      for node n = 2*((nt&1)*16+li) + bit; nt<2 -> r-gates, else u.
#pragma unroll
    for (int nt = 0; nt < 4; ++nt) {
      half8 Ba = *(half8*)&Asrc[(((nt * 2 + 0) * 64) + l) * 8];
      half8 Bb = *(half8*)&Asrc[(((nt * 2 + 1) * 64) + l) * 8];
      const int n = 2 * ((nt & 1) * 16 + li) + bit;
#pragma unroll
      for (int q = 0; q < 2; ++q) {
        f32x4 acc;
#pragma unroll
        for (int qq = 0; qq < 4; ++qq)
          acc[qq] = bjR[q][qq] + xtsR[nt] * w1xR[q][qq];
        acc = mfma16(Aw1[q][0], Ba, acc);
        acc = mfma16(Aw1[q][1], Bb, acc);
        const int jt = 2 * wv + q;
        const int k0 = (jt & 3) * 16 + lq * 4;
        half4 g4;
#pragma unroll
        for (int qq = 0; qq < 4; ++qq)
          g4[qq] = (_Float16)fast_sigmoid(acc[qq]);
        const int fa = afr4(n, k0);
        if (nt < 2) {       // r-gates: rh = r * hsOwn
          half4 hv = *(half4*)&hsOwn[hso4(n, k0)];
          half4 r4 = g4 * hv;
          *(half4*)&A2f[fa] = r4;
        } else {            // u-gates
          *(half4*)&uF[fa] = g4;
        }
      }
    }
    __syncthreads();

    // ---- P2 (swapped): C'[o][n] = w2^T x rh; fused new = u*hs + (1-u)*c
#pragma unroll
    for (int nt = 0; nt < 4; ++nt) {
      half8 Ba = *(half8*)&A2f[(((nt * 2 + 0) * 64) + l) * 8];
      half8 Bb = *(half8*)&A2f[(((nt * 2 + 1) * 64) + l) * 8];
      f32x4 acc;
#pragma unroll
      for (int qq = 0; qq < 4; ++qq)
        acc[qq] = b2R[qq] + xtoR[nt] * w2xR[qq];
      acc = mfma16(Aw2[0], Ba, acc);
      acc = mfma16(Aw2[1], Bb, acc);
      const int n = nt * 16 + li;
      const int o0 = wv * 16 + lq * 4;
      half4 c4;
#pragma unroll
      for (int qq = 0; qq < 4; ++qq)
        c4[qq] = (_Float16)fast_tanh(acc[qq]);
      const int fa = afr4(n, o0);
      half4 uv = *(half4*)&uF[fa];
      half4 hv = *(half4*)&hsOwn[hso4(n, o0)];
      half4 one = {(_Float16)1.f, (_Float16)1.f, (_Float16)1.f, (_Float16)1.f};
      half4 nw = uv * hv + (one - uv) * c4;
      *(half4*)&Asrc[fa] = nw;
    }
    __syncthreads();

    // ---- P3 (swapped): C'[o][n] = wl^T x new + fplC; vector global store
#pragma unroll
    for (int nt = 0; nt < 4; ++nt) {
      half8 Ba = *(half8*)&Asrc[(((nt * 2 + 0) * 64) + l) * 8];
      half8 Bb = *(half8*)&Asrc[(((nt * 2 + 1) * 64) + l) * 8];
      f32x4 acc;
#pragma unroll
      for (int qq = 0; qq < 4; ++qq)
        acc[qq] = (float)fpl4[nt][qq];
      acc = mfma16(Awl[0], Ba, acc);
      acc = mfma16(Awl[1], Bb, acc);
      const int n = nt * 16 + li;
      const int o0 = wv * 16 + lq * 4;
      const size_t base = (size_t)b * 131072 + (size_t)(a + n) * 64 + o0;
      if (outF32) {
        float4 o4 = make_float4(acc[0], acc[1], acc[2], acc[3]);
        *(float4*)&((float*)hs_out_v)[base] = o4;
      } else {
        half4 o4;
#pragma unroll
        for (int qq = 0; qq < 4; ++qq) o4[qq] = (_Float16)acc[qq];
        *(half4*)&((_Float16*)hs_out_v)[base] = o4;
      }
    }
  }
}

// ---------------------------------------------------------------------------
extern "C" void kernel_launch(void* const* d_in, const int* in_sizes, int n_in,
                              void* d_out, int out_size, void* d_ws, size_t ws_size,
                              hipStream_t stream) {
  const float* h      = (const float*)d_in[0];
  const float* adj    = (const float*)d_in[1];
  const float* inputs = (const float*)d_in[2];
  const float* ew1    = (const float*)d_in[3];
  const float* eb1    = (const float*)d_in[4];
  const float* ew2    = (const float*)d_in[5];
  const float* eb2    = (const float*)d_in[6];
  const float* eps1   = (const float*)d_in[7];
  const float* bnw    = (const float*)d_in[8];
  const float* bnb    = (const float*)d_in[9];
  const float* w1     = (const float*)d_in[10];
  const float* b1     = (const float*)d_in[11];
  const float* w2     = (const float*)d_in[12];
  const float* b2     = (const float*)d_in[13];
  const float* wg     = (const float*)d_in[14];
  const float* bg     = (const float*)d_in[15];
  const float* wl_w   = (const float*)d_in[16];
  const float* wl_b   = (const float*)d_in[17];

  char* ws = (char*)d_ws;

  // ws layout (bytes):
  //  [0, 16777216)           h0 (fp16 hs ping)
  //  [16777216, 33554432)    h1 (fp16 hs pong)
  //    aliased pre-GRU inside h1: x1 (131072 f32), x2 (131072 f32),
  //      x1f (131072 f16), psum (4096 f32), pqsum (4096 f32),
  //      scale (64 f32), shift (64 f32)
  //  [33554432, +262144)     fplC (131072 halfs)
  //  then w1f (8192 halfs), w2f (4096), wlf (4096)
  _Float16* h0H = (_Float16*)ws;
  _Float16* h1H = (_Float16*)(ws + 16777216);
  float* x1    = (float*)h1H;
  float* x2    = x1 + 131072;
  _Float16* x1f = (_Float16*)(x2 + 131072);
  float* psum  = (float*)(x1f + 131072);
  float* pqsum = psum + 4096;
  float* scale = pqsum + 4096;
  float* shift = scale + 64;
  _Float16* fplC = (_Float16*)(ws + 33554432);
  _Float16* w1f  = fplC + 131072;
  _Float16* w2f  = w1f + 8192;
  _Float16* wlf  = w2f + 4096;

  extract1<<<512, 256, 0, stream>>>(h, ew1, eb1, x1, x1f);
  extract2_mfma<<<256, 256, 0, stream>>>(adj, x1, x1f, eps1, x2);
  extract3a<<<64, 256, 0, stream>>>(x2, psum, pqsum);
  extract3b<<<1, 64, 0, stream>>>(psum, pqsum, bnw, bnb, scale, shift);
  extract4<<<512, 256, 0, stream>>>(x2, scale, shift, ew2, eb2, wg, bg,
                                    wl_w, wl_b, fplC);
  prep_frags<<<64, 256, 0, stream>>>(w1, w2, wl_w, w1f, w2f, wlf);

  dim3 grid(32, 32);
  for (int t = 0; t < 12; ++t) {
    const _Float16* ibuf = (t & 1) ? h0H : h1H;   // t=0 ignores (first=1)
    void* obuf; int of32 = 0;
    if (t == 11) { obuf = d_out; of32 = 1; }
    else obuf = (t & 1) ? (void*)h1H : (void*)h0H;
    gru_step<<<grid, 256, 0, stream>>>(ibuf, obuf, of32, inputs, t,
                                       (t == 0) ? 1 : 0,
                                       w1, b1, w2, b2, fplC, w1f, w2f, wlf);
  }
}